// Round 2
// baseline (418.581 us; speedup 1.0000x reference)
//
#include <hip/hip_runtime.h>
#include <hip/hip_bf16.h>

// Problem constants (from reference setup_inputs)
constexpr int B  = 4096;    // batch rows
constexpr int D  = 784;     // feature dim
constexpr int O1 = 8192;    // 2-term products
constexpr int O2 = 8192;    // 3-term products
constexpr int OT = O1 + O2; // 16384 output cols per row

constexpr int TPB   = 256;
constexpr int ROWS  = 16;              // rows of x per block
constexpr int LDSTR = 785;             // padded row stride (odd -> bank stride 17,
                                       // 16 rows cover 16 distinct banks: minimal conflicts)
constexpr int CTS   = TPB / ROWS;      // 16 column-threads per block
constexpr int VEC   = 4;               // cols per thread per group (float4 store)
constexpr int CPB   = 2048;            // cols per block (16384/2048 = 8 chunks;
                                       // never straddles the O1 boundary: 8192%2048==0)
constexpr int GROUPS = CPB / (CTS * VEC); // 32

// Lane mapping: r = tid&15 (row), ct = tid>>4 (column-thread).
// A wave = 16 rows x 4 cts. Gather instr: 4 distinct indices x 16 bank-spread
// rows -> max 4-way LDS conflict (vs ~6-way random with col-major lanes).
// Store instr: per row, 4 cts write 4 adjacent float4 = contiguous 64B segment.
__global__ __launch_bounds__(TPB) void randomde_kernel(
    const float* __restrict__ x,
    const int*   __restrict__ idx1,
    const int*   __restrict__ idx2,
    float*       __restrict__ out)
{
    __shared__ float xs[ROWS * LDSTR];

    const int tid     = threadIdx.x;
    const int r       = tid & (ROWS - 1);
    const int ct      = tid >> 4;
    const int row0    = blockIdx.y * ROWS;
    const int colBase = blockIdx.x * CPB;

    // Stage ROWS rows of x into LDS. Scalar ds_writes (padded stride kills
    // 16B alignment for odd rows); global side is coalesced dword loads.
    for (int rr = 0; rr < ROWS; ++rr) {
        const float* __restrict__ src = x + (size_t)(row0 + rr) * D;
        #pragma unroll
        for (int c = tid; c < D; c += TPB) {
            xs[rr * LDSTR + c] = src[c];
        }
    }
    __syncthreads();

    const float* __restrict__ xrow = &xs[r * LDSTR];
    float* __restrict__ outrow = out + (size_t)(row0 + r) * OT;

    if (colBase < O1) {
        // 2-term region. idx1 for 4 cols = 8 consecutive ints = 2 x int4 (32B aligned).
        for (int g = 0; g < GROUPS; ++g) {
            const int c = colBase + g * (CTS * VEC) + ct * VEC;
            const int4* __restrict__ p = (const int4*)(idx1 + (size_t)c * 2);
            const int4 i0 = p[0];
            const int4 i1 = p[1];
            float4 v;
            v.x = xrow[i0.x] * xrow[i0.y];
            v.y = xrow[i0.z] * xrow[i0.w];
            v.z = xrow[i1.x] * xrow[i1.y];
            v.w = xrow[i1.z] * xrow[i1.w];
            *(float4*)(outrow + c) = v;
        }
    } else {
        // 3-term region. idx2 for 4 cols = 12 consecutive ints = 3 x int4 (48B, 16B aligned).
        for (int g = 0; g < GROUPS; ++g) {
            const int c  = colBase + g * (CTS * VEC) + ct * VEC;
            const int c2 = c - O1;
            const int4* __restrict__ p = (const int4*)(idx2 + (size_t)c2 * 3);
            const int4 i0 = p[0];
            const int4 i1 = p[1];
            const int4 i2 = p[2];
            float4 v;
            v.x = xrow[i0.x] * xrow[i0.y] * xrow[i0.z];
            v.y = xrow[i0.w] * xrow[i1.x] * xrow[i1.y];
            v.z = xrow[i1.z] * xrow[i1.w] * xrow[i2.x];
            v.w = xrow[i2.y] * xrow[i2.z] * xrow[i2.w];
            *(float4*)(outrow + c) = v;
        }
    }
}

extern "C" void kernel_launch(void* const* d_in, const int* in_sizes, int n_in,
                              void* d_out, int out_size, void* d_ws, size_t ws_size,
                              hipStream_t stream) {
    const float* x    = (const float*)d_in[0];
    const int*   idx1 = (const int*)d_in[1];
    const int*   idx2 = (const int*)d_in[2];
    float*       out  = (float*)d_out;

    dim3 grid(OT / CPB, B / ROWS);  // (8, 256) = 2048 blocks
    dim3 block(TPB);
    randomde_kernel<<<grid, block, 0, stream>>>(x, idx1, idx2, out);
}

// Round 3
// 288.999 us; speedup vs baseline: 1.4484x; 1.4484x over previous
//
#include <hip/hip_runtime.h>
#include <hip/hip_bf16.h>

// Problem constants (from reference setup_inputs)
constexpr int B  = 4096;    // batch rows
constexpr int D  = 784;     // feature dim
constexpr int O1 = 8192;    // 2-term products
constexpr int O2 = 8192;    // 3-term products
constexpr int OT = O1 + O2; // 16384 output cols per row

constexpr int TPB  = 256;
constexpr int ROWS = 4;     // rows per block -> LDS = 4*784*4 = 12544 B (occupancy-friendly)
constexpr int VEC  = 4;     // cols per thread per group (float4 store)
constexpr int CPB  = 2048;  // cols per block = 2 groups of TPB*VEC; 8192%2048==0 so
                            // a block never straddles the out1/out2 boundary
constexpr int GROUPS = CPB / (TPB * VEC); // 2

// Occupancy-first design: 12.5 KB LDS + VGPR<=64 (launch_bounds 8 waves/EU)
// -> 32 waves/CU. Lanes are column-major: each ds_read gathers 64 random
// indices from ONE row (~2x bank-conflict penalty, measured ~20K cyc/CU —
// cheap). Stores: wave writes 64 adjacent float4 = 1 KiB contiguous.
__global__ __launch_bounds__(TPB, 8) void randomde_kernel(
    const float* __restrict__ x,
    const int*   __restrict__ idx1,
    const int*   __restrict__ idx2,
    float*       __restrict__ out)
{
    __shared__ float xs[ROWS][D];

    const int tid     = threadIdx.x;
    const int row0    = blockIdx.y * ROWS;
    const int colBase = blockIdx.x * CPB;

    // Stage 4 contiguous rows of x into LDS with float4 loads (16B aligned:
    // row0*D*4 = 12544*blockIdx.y bytes).
    {
        const float4* __restrict__ x4 = (const float4*)(x + (size_t)row0 * D);
        float4* xs4 = (float4*)&xs[0][0];
        constexpr int N4 = ROWS * (D / 4);   // 784
        for (int i = tid; i < N4; i += TPB) {
            xs4[i] = x4[i];
        }
    }
    __syncthreads();

    const int c0 = colBase + tid * VEC;      // group 0 column; group 1 = c0 + TPB*VEC

    if (colBase < O1) {
        // ---- 2-term region: idx for 4 cols = 2 int4 (32B aligned) ----
        int4 p[GROUPS][2];
        #pragma unroll
        for (int g = 0; g < GROUPS; ++g) {
            const int4* __restrict__ ip = (const int4*)(idx1 + (size_t)(c0 + g * TPB * VEC) * 2);
            p[g][0] = ip[0];
            p[g][1] = ip[1];
        }
        #pragma unroll
        for (int g = 0; g < GROUPS; ++g) {
            const int c = c0 + g * TPB * VEC;
            const int4 i0 = p[g][0], i1 = p[g][1];
            #pragma unroll
            for (int r = 0; r < ROWS; ++r) {
                float4 v;
                v.x = xs[r][i0.x] * xs[r][i0.y];
                v.y = xs[r][i0.z] * xs[r][i0.w];
                v.z = xs[r][i1.x] * xs[r][i1.y];
                v.w = xs[r][i1.z] * xs[r][i1.w];
                *(float4*)(out + (size_t)(row0 + r) * OT + c) = v;
            }
        }
    } else {
        // ---- 3-term region: idx for 4 cols = 3 int4 (16B aligned) ----
        int4 p[GROUPS][3];
        #pragma unroll
        for (int g = 0; g < GROUPS; ++g) {
            const int4* __restrict__ ip = (const int4*)(idx2 + (size_t)(c0 - O1 + g * TPB * VEC) * 3);
            p[g][0] = ip[0];
            p[g][1] = ip[1];
            p[g][2] = ip[2];
        }
        #pragma unroll
        for (int g = 0; g < GROUPS; ++g) {
            const int c = c0 + g * TPB * VEC;
            const int4 i0 = p[g][0], i1 = p[g][1], i2 = p[g][2];
            #pragma unroll
            for (int r = 0; r < ROWS; ++r) {
                float4 v;
                v.x = xs[r][i0.x] * xs[r][i0.y] * xs[r][i0.z];
                v.y = xs[r][i0.w] * xs[r][i1.x] * xs[r][i1.y];
                v.z = xs[r][i1.z] * xs[r][i1.w] * xs[r][i2.x];
                v.w = xs[r][i2.y] * xs[r][i2.z] * xs[r][i2.w];
                *(float4*)(out + (size_t)(row0 + r) * OT + c) = v;
            }
        }
    }
}

extern "C" void kernel_launch(void* const* d_in, const int* in_sizes, int n_in,
                              void* d_out, int out_size, void* d_ws, size_t ws_size,
                              hipStream_t stream) {
    const float* x    = (const float*)d_in[0];
    const int*   idx1 = (const int*)d_in[1];
    const int*   idx2 = (const int*)d_in[2];
    float*       out  = (float*)d_out;

    dim3 grid(OT / CPB, B / ROWS);  // (8, 1024) = 8192 blocks
    dim3 block(TPB);
    randomde_kernel<<<grid, block, 0, stream>>>(x, idx1, idx2, out);
}